// Round 1
// 681.355 us; speedup vs baseline: 1.0162x; 1.0162x over previous
//
#include <hip/hip_runtime.h>
#include <math.h>

#define T_LEN 4000
#define T4    1000
#define BDIM  256
#define EPS   0.01f

typedef float v4f __attribute__((ext_vector_type(4)));

__device__ __forceinline__ float waveReduceSum(float v) {
    #pragma unroll
    for (int off = 32; off > 0; off >>= 1) v += __shfl_down(v, off, 64);
    return v;
}

// -------------------------------------------------------------------------
// Kernel 1: per-(b,c) row stats of x_a+x_b over T, single streaming pass.
// Raw power sums S1..S4 -> central moments algebraically.
// stats layout [B, 4C]: [mean | std | skew | kurt]
// 3+1 explicit unroll: all loads issued up front (T4 = 3*BDIM + 232).
// Normal (caching) loads on purpose: the tail of this stream stays resident
// in the 256 MiB Infinity Cache for the reverse-order blend pass.
// -------------------------------------------------------------------------
__global__ __launch_bounds__(BDIM) void stats_kernel(
    const float* __restrict__ xa, const float* __restrict__ xb,
    float* __restrict__ stats, int C) {
    __shared__ float red[4][4];             // [wave][S1..S4]

    const int r = blockIdx.x;               // b*C + c
    const int b = r / C;
    const int c = r - b * C;
    const int tid = threadIdx.x;
    const int wave = tid >> 6, lane = tid & 63;

    const v4f* a4 = (const v4f*)(xa + (size_t)r * T_LEN);
    const v4f* b4 = (const v4f*)(xb + (size_t)r * T_LEN);

    const bool has4 = (tid < (T4 - 3 * BDIM));   // 232 threads take a 4th chunk
    v4f av0 = a4[tid];
    v4f bv0 = b4[tid];
    v4f av1 = a4[tid + BDIM];
    v4f bv1 = b4[tid + BDIM];
    v4f av2 = a4[tid + 2 * BDIM];
    v4f bv2 = b4[tid + 2 * BDIM];
    v4f av3 = {0.f, 0.f, 0.f, 0.f};
    v4f bv3 = {0.f, 0.f, 0.f, 0.f};
    if (has4) { av3 = a4[tid + 3 * BDIM]; bv3 = b4[tid + 3 * BDIM]; }

    float s1 = 0.f, s2 = 0.f, s3 = 0.f, s4 = 0.f;
    // zero-filled 4th chunk contributes exact +0.0 to every sum -> no guard
    #define ACC(av, bv)                                                      \
    {                                                                        \
        float x0 = av.x + bv.x, x1 = av.y + bv.y,                            \
              x2 = av.z + bv.z, x3 = av.w + bv.w;                            \
        float q0 = x0 * x0, q1 = x1 * x1, q2 = x2 * x2, q3 = x3 * x3;        \
        s1 += (x0 + x1) + (x2 + x3);                                         \
        s2 += (q0 + q1) + (q2 + q3);                                         \
        s3 += (q0 * x0 + q1 * x1) + (q2 * x2 + q3 * x3);                     \
        s4 += (q0 * q0 + q1 * q1) + (q2 * q2 + q3 * q3);                     \
    }
    ACC(av0, bv0)
    ACC(av1, bv1)
    ACC(av2, bv2)
    ACC(av3, bv3)
    #undef ACC

    s1 = waveReduceSum(s1);
    s2 = waveReduceSum(s2);
    s3 = waveReduceSum(s3);
    s4 = waveReduceSum(s4);
    if (lane == 0) { red[wave][0] = s1; red[wave][1] = s2; red[wave][2] = s3; red[wave][3] = s4; }
    __syncthreads();

    if (tid == 0) {
        float S1 = red[0][0] + red[1][0] + red[2][0] + red[3][0];
        float S2 = red[0][1] + red[1][1] + red[2][1] + red[3][1];
        float S3 = red[0][2] + red[1][2] + red[2][2] + red[3][2];
        float S4 = red[0][3] + red[1][3] + red[2][3] + red[3][3];
        const float invT = 1.0f / T_LEN;
        float mean = S1 * invT;
        float m = mean, m2c = m * m;
        float M2 = S2 - S1 * m;
        float M3 = S3 - 3.0f * m * S2 + 2.0f * m2c * S1;
        float M4 = S4 - 4.0f * m * S3 + 6.0f * m2c * S2 - 3.0f * m2c * m * S1;
        float var_b = M2 / (float)(T_LEN - 1);
        float sd = sqrtf(fmaxf(var_b, 0.0f));
        float d = fmaxf(sd, EPS);
        float inv = 1.0f / d;
        float inv2 = inv * inv;
        float skew = (M3 * invT) * inv2 * inv;
        float kurt = (M4 * invT) * inv2 * inv2;
        float* srow = stats + (size_t)b * (4 * C);
        srow[c]         = mean;
        srow[C + c]     = sd;
        srow[2 * C + c] = skew;
        srow[3 * C + c] = kurt;
    }
}

// -------------------------------------------------------------------------
// Kernel 2: h[b,o] = b1[o] + sum_j stats[b,j] * W1[o,j]   (W1: [C, 4C])
// One wave per output o; grid = B * C/4, block = 4 waves.
// -------------------------------------------------------------------------
__global__ __launch_bounds__(BDIM) void h_kernel(
    const float* __restrict__ stats, const float* __restrict__ W1,
    const float* __restrict__ b1, float* __restrict__ h, int C) {
    __shared__ __align__(16) float sst[2048];   // stats row, 8 KB
    const int H = 4 * C;
    const int groups = C / 4;
    const int b = blockIdx.x / groups;
    const int grp = blockIdx.x - b * groups;
    const int tid = threadIdx.x;
    const int wave = tid >> 6, lane = tid & 63;
    const int o = grp * 4 + wave;

    const v4f* src4 = (const v4f*)(stats + (size_t)b * H);
    v4f* sst4 = (v4f*)sst;
    for (int i = tid; i < H / 4; i += BDIM) sst4[i] = src4[i];
    __syncthreads();

    const v4f* s4 = (const v4f*)sst;
    const v4f* w4 = (const v4f*)(W1 + (size_t)o * H);
    float acc = 0.f;
    #pragma unroll
    for (int it = 0; it < 8; ++it) {            // 8*64 = 512 = H/4 exactly
        int idx = it * 64 + lane;
        v4f w = w4[idx];
        v4f s = s4[idx];
        acc += (w.x * s.x + w.y * s.y) + (w.z * s.z + w.w * s.w);
    }
    acc = waveReduceSum(acc);
    if (lane == 0) h[(size_t)b * C + o] = acc + b1[o];
}

// -------------------------------------------------------------------------
// Kernel 3: gate g[b,c] = sigmoid(L0 - L1), L_k = h[b,:].W2[k,c,:] + b2[k,c]
// One wave per c (computes both branch dots); 4 c's per block share the
// LDS-staged h row. Grid = B * C/4. All operands L2-resident.
// -------------------------------------------------------------------------
__global__ __launch_bounds__(BDIM) void gate_kernel(
    const float* __restrict__ h, const float* __restrict__ W2,
    const float* __restrict__ b2, float* __restrict__ g, int C) {
    __shared__ __align__(16) float hs[512];
    const int groups = C / 4;
    const int b  = blockIdx.x / groups;
    const int cg = blockIdx.x - b * groups;
    const int tid = threadIdx.x;
    const int wave = tid >> 6, lane = tid & 63;
    const int c = cg * 4 + wave;

    for (int i = tid; i < C; i += BDIM) hs[i] = h[(size_t)b * C + i];
    __syncthreads();

    const v4f* h4 = (const v4f*)hs;
    const v4f* w0 = (const v4f*)(W2 + (size_t)c * C);
    const v4f* w1 = (const v4f*)(W2 + (size_t)C * C + (size_t)c * C);
    float l0 = 0.f, l1 = 0.f;
    #pragma unroll
    for (int it = 0; it < 2; ++it) {            // 2*64 = 128 = C/4 exactly
        int i = it * 64 + lane;
        v4f hv = h4[i];
        v4f a0 = w0[i];
        v4f a1 = w1[i];
        l0 += (hv.x * a0.x + hv.y * a0.y) + (hv.z * a0.z + hv.w * a0.w);
        l1 += (hv.x * a1.x + hv.y * a1.y) + (hv.z * a1.z + hv.w * a1.w);
    }
    l0 = waveReduceSum(l0);
    l1 = waveReduceSum(l1);
    if (lane == 0) {
        float L0 = l0 + b2[c];
        float L1 = l1 + b2[C + c];
        g[(size_t)b * C + c] = 1.0f / (1.0f + expf(L1 - L0));
    }
}

// -------------------------------------------------------------------------
// Kernel 4: pure streaming blend, out = g*xa + (1-g)*xb.
// Rows processed in REVERSE dispatch order: the tail of the stats pass
// (~8192 rows = 256 MiB of xa+xb) is still resident in Infinity Cache, so
// the first reads here are L3 hits. Nontemporal loads/stores keep this
// pass from evicting those lines (out is never re-read; these rows are
// never re-read either).
// -------------------------------------------------------------------------
__global__ __launch_bounds__(BDIM) void blend_kernel(
    const float* __restrict__ xa, const float* __restrict__ xb,
    const float* __restrict__ g, float* __restrict__ out) {
    const int r = (int)gridDim.x - 1 - (int)blockIdx.x;   // reverse order
    const int tid = threadIdx.x;

    const v4f* a4 = (const v4f*)(xa + (size_t)r * T_LEN);
    const v4f* b4 = (const v4f*)(xb + (size_t)r * T_LEN);
    v4f* o4 = (v4f*)(out + (size_t)r * T_LEN);

    const bool has4 = (tid < (T4 - 3 * BDIM));
    v4f A0 = __builtin_nontemporal_load(a4 + tid);
    v4f B0 = __builtin_nontemporal_load(b4 + tid);
    v4f A1 = __builtin_nontemporal_load(a4 + tid + BDIM);
    v4f B1 = __builtin_nontemporal_load(b4 + tid + BDIM);
    v4f A2 = __builtin_nontemporal_load(a4 + tid + 2 * BDIM);
    v4f B2 = __builtin_nontemporal_load(b4 + tid + 2 * BDIM);
    v4f A3 = {0.f, 0.f, 0.f, 0.f};
    v4f B3 = {0.f, 0.f, 0.f, 0.f};
    if (has4) {
        A3 = __builtin_nontemporal_load(a4 + tid + 3 * BDIM);
        B3 = __builtin_nontemporal_load(b4 + tid + 3 * BDIM);
    }

    const float gv = g[r];                  // uniform address -> broadcast
    const float hg = 1.0f - gv;

    v4f O0 = A0 * gv + B0 * hg;
    v4f O1 = A1 * gv + B1 * hg;
    v4f O2 = A2 * gv + B2 * hg;
    __builtin_nontemporal_store(O0, o4 + tid);
    __builtin_nontemporal_store(O1, o4 + tid + BDIM);
    __builtin_nontemporal_store(O2, o4 + tid + 2 * BDIM);
    if (has4) {
        v4f O3 = A3 * gv + B3 * hg;
        __builtin_nontemporal_store(O3, o4 + tid + 3 * BDIM);
    }
}

extern "C" void kernel_launch(void* const* d_in, const int* in_sizes, int n_in,
                              void* d_out, int out_size, void* d_ws, size_t ws_size,
                              hipStream_t stream) {
    const float* xa = (const float*)d_in[0];   // [B, C, T]
    const float* xb = (const float*)d_in[1];   // [B, C, T]
    const float* W1 = (const float*)d_in[2];   // [C, 4C]
    const float* b1 = (const float*)d_in[3];   // [C]
    const float* W2 = (const float*)d_in[4];   // [2, C, C]
    const float* b2 = (const float*)d_in[5];   // [2, C]
    float* out = (float*)d_out;

    const int C = in_sizes[3];                 // 512
    const int B = in_sizes[0] / (C * T_LEN);   // 32

    // workspace layout
    float* stats = (float*)d_ws;                       // B * 4C
    float* h     = stats + (size_t)B * 4 * C;          // B * C
    float* g     = stats;                              // reuse: stats dead after h_kernel

    stats_kernel<<<B * C, BDIM, 0, stream>>>(xa, xb, stats, C);
    h_kernel<<<B * (C / 4), BDIM, 0, stream>>>(stats, W1, b1, h, C);
    gate_kernel<<<B * (C / 4), BDIM, 0, stream>>>(h, W2, b2, g, C);
    blend_kernel<<<B * C, BDIM, 0, stream>>>(xa, xb, g, out);
}